// Round 1
// baseline (167.658 us; speedup 1.0000x reference)
//
#include <hip/hip_runtime.h>

// K1: mean-aggregation. One 64-lane wave per target node; lane = feature dim.
__global__ __launch_bounds__(256) void sage_agg(
    const float* __restrict__ x, const int* __restrict__ row,
    const int* __restrict__ colptr, float* __restrict__ agg, int N) {
  int wid  = (int)((blockIdx.x * 4u) + (threadIdx.x >> 6));
  int lane = threadIdx.x & 63;
  if (wid >= N) return;
  int s = colptr[wid];
  int e = colptr[wid + 1];
  float acc = 0.0f;
  int t = s;
  // unroll-by-4 so the 4 gather loads are in flight together
  for (; t + 3 < e; t += 4) {
    int r0 = row[t + 0], r1 = row[t + 1], r2 = row[t + 2], r3 = row[t + 3];
    float v0 = x[(size_t)r0 * 64 + lane];
    float v1 = x[(size_t)r1 * 64 + lane];
    float v2 = x[(size_t)r2 * 64 + lane];
    float v3 = x[(size_t)r3 * 64 + lane];
    acc += (v0 + v1) + (v2 + v3);
  }
  for (; t < e; ++t) acc += x[(size_t)row[t] * 64 + lane];
  int deg = e - s;
  float scale = (deg > 0) ? (1.0f / (float)deg) : 0.0f;
  agg[(size_t)wid * 64 + lane] = acc * scale;
}

// K2: out[n] = b + W_agg @ agg[n] + W_x @ x[n], in-place on d_out (agg lives there).
// thread = node; acc[64] in VGPRs; W^T in LDS, broadcast float4 reads.
__global__ __launch_bounds__(256) void sage_gemm(
    const float* __restrict__ x, const float* __restrict__ W,
    const float* __restrict__ b, float* __restrict__ out, int N) {
  __shared__ float wt[128][64];   // wt[k][j] = W[j*128 + k]   (32 KB)
  __shared__ float ft[256][65];   // feat tile, +1 pad -> conflict-free (66.5 KB)
  __shared__ float bs[64];

  int tid = threadIdx.x;
  for (int i = tid; i < 128 * 64; i += 256) {
    int j = i >> 7, k = i & 127;
    wt[k][j] = W[i];
  }
  if (tid < 64) bs[tid] = b[tid];
  __syncthreads();

  float acc[64];
  #pragma unroll
  for (int j = 0; j < 64; ++j) acc[j] = bs[j];

  int n0   = blockIdx.x * 256;
  int rows = N - n0; if (rows > 256) rows = 256;

  // ---- phase 1: aggregated features (currently stored in out) ----
  {
    const float* src = out + (size_t)n0 * 64;
    for (int i = tid; i < rows * 64; i += 256) ft[i >> 6][i & 63] = src[i];
  }
  __syncthreads();
  if (tid < rows) {
    #pragma unroll 2
    for (int k = 0; k < 64; ++k) {
      float f = ft[tid][k];
      #pragma unroll
      for (int q = 0; q < 16; ++q) {
        float4 w4 = *(const float4*)&wt[k][q * 4];
        acc[q * 4 + 0] = fmaf(w4.x, f, acc[q * 4 + 0]);
        acc[q * 4 + 1] = fmaf(w4.y, f, acc[q * 4 + 1]);
        acc[q * 4 + 2] = fmaf(w4.z, f, acc[q * 4 + 2]);
        acc[q * 4 + 3] = fmaf(w4.w, f, acc[q * 4 + 3]);
      }
    }
  }
  __syncthreads();

  // ---- phase 2: root features x ----
  {
    const float* src = x + (size_t)n0 * 64;
    for (int i = tid; i < rows * 64; i += 256) ft[i >> 6][i & 63] = src[i];
  }
  __syncthreads();
  if (tid < rows) {
    #pragma unroll 2
    for (int k = 0; k < 64; ++k) {
      float f = ft[tid][k];
      #pragma unroll
      for (int q = 0; q < 16; ++q) {
        float4 w4 = *(const float4*)&wt[64 + k][q * 4];
        acc[q * 4 + 0] = fmaf(w4.x, f, acc[q * 4 + 0]);
        acc[q * 4 + 1] = fmaf(w4.y, f, acc[q * 4 + 1]);
        acc[q * 4 + 2] = fmaf(w4.z, f, acc[q * 4 + 2]);
        acc[q * 4 + 3] = fmaf(w4.w, f, acc[q * 4 + 3]);
      }
    }
  }
  __syncthreads();

  // ---- stage result through LDS for coalesced global stores ----
  if (tid < rows) {
    #pragma unroll
    for (int j = 0; j < 64; ++j) ft[tid][j] = acc[j];
  }
  __syncthreads();
  {
    float* dst = out + (size_t)n0 * 64;
    for (int i = tid; i < rows * 64; i += 256) dst[i] = ft[i >> 6][i & 63];
  }
}

extern "C" void kernel_launch(void* const* d_in, const int* in_sizes, int n_in,
                              void* d_out, int out_size, void* d_ws, size_t ws_size,
                              hipStream_t stream) {
  const float* x      = (const float*)d_in[0];
  const int*   row    = (const int*)d_in[1];
  const int*   colptr = (const int*)d_in[2];
  const float* W      = (const float*)d_in[3];
  const float* b      = (const float*)d_in[4];
  float* out = (float*)d_out;

  int N = in_sizes[0] / 64;   // x is [N, 64]

  // K1: 4 waves (nodes) per 256-thread block
  int nb1 = (N + 3) / 4;
  sage_agg<<<nb1, 256, 0, stream>>>(x, row, colptr, out, N);

  // K2: 256 nodes per block, in-place on out
  int nb2 = (N + 255) / 256;
  sage_gemm<<<nb2, 256, 0, stream>>>(x, W, b, out, N);
}

// Round 2
// 94.710 us; speedup vs baseline: 1.7702x; 1.7702x over previous
//
#include <hip/hip_runtime.h>

typedef __bf16 bf16x8 __attribute__((ext_vector_type(8)));
typedef float  f32x4  __attribute__((ext_vector_type(4)));

__device__ __forceinline__ unsigned short f2bf(float f) {
  unsigned u = __float_as_uint(f);
  u = u + 0x7fffu + ((u >> 16) & 1u);   // round-to-nearest-even
  return (unsigned short)(u >> 16);
}
__device__ __forceinline__ float bf2f(unsigned short h) {
  return __uint_as_float(((unsigned)h) << 16);
}

// K0: convert x (f32) -> xb (bf16), 8 elems/thread
__global__ __launch_bounds__(256) void cvt_bf16(
    const float* __restrict__ x, unsigned short* __restrict__ xb, int total8) {
  int i = blockIdx.x * 256 + threadIdx.x;
  if (i >= total8) return;
  const float4* p = (const float4*)(x + (size_t)i * 8);
  float4 a = p[0], b = p[1];
  union { unsigned short u[8]; uint4 v; } r;
  r.u[0] = f2bf(a.x); r.u[1] = f2bf(a.y); r.u[2] = f2bf(a.z); r.u[3] = f2bf(a.w);
  r.u[4] = f2bf(b.x); r.u[5] = f2bf(b.y); r.u[6] = f2bf(b.z); r.u[7] = f2bf(b.w);
  ((uint4*)xb)[i] = r.v;
}

// K1: mean aggregation; wave per node, lane = feature. 8 gathers in flight.
template <bool BF>
__global__ __launch_bounds__(256) void sage_agg(
    const float* __restrict__ x, const unsigned short* __restrict__ xb,
    const int* __restrict__ row, const int* __restrict__ colptr,
    float* __restrict__ agg, int N) {
  int wid  = blockIdx.x * 4 + (threadIdx.x >> 6);
  int lane = threadIdx.x & 63;
  if (wid >= N) return;
  int s = colptr[wid], e = colptr[wid + 1];
  float acc = 0.0f;
  int t = s;
#define LDX(r) (BF ? bf2f(xb[(size_t)(r) * 64 + lane]) : x[(size_t)(r) * 64 + lane])
  for (; t + 8 <= e; t += 8) {
    int r0 = row[t],     r1 = row[t + 1], r2 = row[t + 2], r3 = row[t + 3];
    int r4 = row[t + 4], r5 = row[t + 5], r6 = row[t + 6], r7 = row[t + 7];
    float v0 = LDX(r0), v1 = LDX(r1), v2 = LDX(r2), v3 = LDX(r3);
    float v4 = LDX(r4), v5 = LDX(r5), v6 = LDX(r6), v7 = LDX(r7);
    acc += ((v0 + v1) + (v2 + v3)) + ((v4 + v5) + (v6 + v7));
  }
  for (; t + 4 <= e; t += 4) {
    int r0 = row[t], r1 = row[t + 1], r2 = row[t + 2], r3 = row[t + 3];
    float v0 = LDX(r0), v1 = LDX(r1), v2 = LDX(r2), v3 = LDX(r3);
    acc += (v0 + v1) + (v2 + v3);
  }
  for (; t < e; ++t) acc += LDX(row[t]);
#undef LDX
  int deg = e - s;
  agg[(size_t)wid * 64 + lane] = (deg > 0) ? (acc / (float)deg) : 0.0f;
}

// K2: out[n] = b + [agg|x] @ W^T via bf16 MFMA 16x16x32.
// Block = 256 thr = 4 waves, 128 nodes. W fragments live in VGPRs (layout of
// W [out][in] row-major == B-fragment layout: lane l holds W[col=l&15][k-chunk]).
// feat tile in LDS: ft[node][k] bf16, stride 136 (pad 8) -> <=2-way bank alias.
template <bool BF>
__global__ __launch_bounds__(256) void sage_mm(
    const float* __restrict__ x, const unsigned short* __restrict__ xb,
    const float* __restrict__ W, const float* __restrict__ b,
    float* __restrict__ out, int N) {
  __shared__ unsigned short ft[128][136];   // 34 KB
  int tid = threadIdx.x;
  int l = tid & 63, w = tid >> 6;
  int colr = l & 15, kg = l >> 4;           // kg in 0..3
  int n0 = blockIdx.x * 128;
  int rows = N - n0; if (rows > 128) rows = 128;

  // ---- B fragments (W) + bias, straight from global, f32 -> bf16 ----
  bf16x8 bfrag[4][4];
  float bias[4];
  #pragma unroll
  for (int c = 0; c < 4; ++c) {
    bias[c] = b[c * 16 + colr];
    #pragma unroll
    for (int kq = 0; kq < 4; ++kq) {
      const float* wp = W + (size_t)(c * 16 + colr) * 128 + kq * 32 + kg * 8;
      float4 wa = *(const float4*)wp;
      float4 wb = *(const float4*)(wp + 4);
      union { unsigned short u[8]; bf16x8 v; } r;
      r.u[0] = f2bf(wa.x); r.u[1] = f2bf(wa.y); r.u[2] = f2bf(wa.z); r.u[3] = f2bf(wa.w);
      r.u[4] = f2bf(wb.x); r.u[5] = f2bf(wb.y); r.u[6] = f2bf(wb.z); r.u[7] = f2bf(wb.w);
      bfrag[c][kq] = r.v;
    }
  }

  // ---- stage feat tile: k 0..63 = agg (read from out), k 64..127 = x ----
  const float* aggsrc = out + (size_t)n0 * 64;
  #pragma unroll
  for (int it = 0; it < 4; ++it) {
    int flat = it * 2048 + tid * 8;
    int n = flat >> 6, k = flat & 63;
    { // agg half
      union { unsigned short u[8]; uint4 v; } r;
      if (n < rows) {
        const float4* p = (const float4*)(aggsrc + (size_t)n * 64 + k);
        float4 a = p[0], bb = p[1];
        r.u[0] = f2bf(a.x);  r.u[1] = f2bf(a.y);  r.u[2] = f2bf(a.z);  r.u[3] = f2bf(a.w);
        r.u[4] = f2bf(bb.x); r.u[5] = f2bf(bb.y); r.u[6] = f2bf(bb.z); r.u[7] = f2bf(bb.w);
      } else { r.v = make_uint4(0, 0, 0, 0); }
      *(uint4*)&ft[n][k] = r.v;
    }
    { // x half
      uint4 v;
      if (BF) {
        v = (n < rows) ? *(const uint4*)(xb + ((size_t)(n0 + n) * 64 + k))
                       : make_uint4(0, 0, 0, 0);
      } else {
        union { unsigned short u[8]; uint4 vv; } r;
        if (n < rows) {
          const float4* p = (const float4*)(x + (size_t)(n0 + n) * 64 + k);
          float4 a = p[0], bb = p[1];
          r.u[0] = f2bf(a.x);  r.u[1] = f2bf(a.y);  r.u[2] = f2bf(a.z);  r.u[3] = f2bf(a.w);
          r.u[4] = f2bf(bb.x); r.u[5] = f2bf(bb.y); r.u[6] = f2bf(bb.z); r.u[7] = f2bf(bb.w);
        } else { r.vv = make_uint4(0, 0, 0, 0); }
        v = r.vv;
      }
      *(uint4*)&ft[n][64 + k] = v;
    }
  }
  __syncthreads();   // after this, all reads of out-slice are done; stores below are safe

  // ---- MFMA: wave w owns rows [w*32, w*32+32), all 64 cols ----
  f32x4 acc[2][4];
  #pragma unroll
  for (int m = 0; m < 2; ++m)
    #pragma unroll
    for (int c = 0; c < 4; ++c)
      acc[m][c] = (f32x4){bias[c], bias[c], bias[c], bias[c]};

  #pragma unroll
  for (int kq = 0; kq < 4; ++kq) {
    bf16x8 a0 = *(const bf16x8*)&ft[w * 32 + colr][kq * 32 + kg * 8];
    bf16x8 a1 = *(const bf16x8*)&ft[w * 32 + 16 + colr][kq * 32 + kg * 8];
    #pragma unroll
    for (int c = 0; c < 4; ++c) {
      acc[0][c] = __builtin_amdgcn_mfma_f32_16x16x32_bf16(a0, bfrag[c][kq], acc[0][c], 0, 0, 0);
      acc[1][c] = __builtin_amdgcn_mfma_f32_16x16x32_bf16(a1, bfrag[c][kq], acc[1][c], 0, 0, 0);
    }
  }

  // ---- store: C/D layout col=l&15, row=(l>>4)*4+r ----
  #pragma unroll
  for (int m = 0; m < 2; ++m) {
    int nodeb = n0 + w * 32 + m * 16 + kg * 4;
    #pragma unroll
    for (int c = 0; c < 4; ++c) {
      #pragma unroll
      for (int r = 0; r < 4; ++r) {
        int node = nodeb + r;
        if (node < N) out[(size_t)node * 64 + c * 16 + colr] = acc[m][c][r];
      }
    }
  }
}

extern "C" void kernel_launch(void* const* d_in, const int* in_sizes, int n_in,
                              void* d_out, int out_size, void* d_ws, size_t ws_size,
                              hipStream_t stream) {
  const float* x      = (const float*)d_in[0];
  const int*   row    = (const int*)d_in[1];
  const int*   colptr = (const int*)d_in[2];
  const float* W      = (const float*)d_in[3];
  const float* b      = (const float*)d_in[4];
  float* out = (float*)d_out;

  int N = in_sizes[0] / 64;
  bool bf = ws_size >= (size_t)N * 64 * sizeof(unsigned short);
  unsigned short* xb = (unsigned short*)d_ws;

  if (bf) {
    int total8 = N * 8;   // N*64/8 vector-chunks
    cvt_bf16<<<(total8 + 255) / 256, 256, 0, stream>>>(x, xb, total8);
    sage_agg<true><<<(N + 3) / 4, 256, 0, stream>>>(x, xb, row, colptr, out, N);
    sage_mm<true><<<(N + 127) / 128, 256, 0, stream>>>(x, xb, W, b, out, N);
  } else {
    sage_agg<false><<<(N + 3) / 4, 256, 0, stream>>>(x, xb, row, colptr, out, N);
    sage_mm<false><<<(N + 127) / 128, 256, 0, stream>>>(x, xb, W, b, out, N);
  }
}